// Round 12
// baseline (1536.531 us; speedup 1.0000x reference)
//
#include <hip/hip_runtime.h>
#include <math.h>

// ---------------------------------------------------------------------------
// GP posterior mean:
//   k_outer : separable NUFFT outer products, fp32 atomic-free partials.
//   k_reduce: partials -> fp32 circulant table vcf + fp64 rhs b.
//   k_cg_solve: ONE launch, ONE 1024-thread block; 50 CG iterations, Toeplitz
//     apply as in-LDS 128x128 FFT conv, fused stages, STATIC reg indexing
//     (R10: dynamic indexing -> scratch), pad-17 LDS layout (conflict-free).
//     R12: pk-form complex mul (v_pk_fma instead of scalar — R11 VALU was
//     ~2x packed rate); ONE reduce/iter via (pAp, rAp, ApAp) + rz recurrence
//     rz+ = rz - 2a<r,Ap> + a^2|Ap|^2 (algebra verified R4-R7, absmax 1024);
//     scatter z folded into update loop. Barriers/iter 10 -> 9.
//   k_eval  : posterior mean at test points from al = ws*x_50.
// ---------------------------------------------------------------------------

typedef float f2 __attribute__((ext_vector_type(2)));
#define PB 16
#define RS 137          // Z row stride in f2 (8 blocks x 17)

__device__ inline f2 f2s(float s) { return (f2){s, s}; }
// pk-friendly complex mul: 1 pk_mul + 1 pk_fma (+neg modifier)
__device__ inline f2 cmulf(f2 a, f2 b) {   // a*b
    f2 br = (f2){-b.y, b.x};
    return f2s(a.x) * b + f2s(a.y) * br;
}
__device__ inline f2 cmulcf(f2 a, f2 b) {  // a*conj(b)
    f2 bc = (f2){b.x, -b.y};
    f2 bs = (f2){b.y, b.x};
    return f2s(a.x) * bc + f2s(a.y) * bs;
}
__device__ inline int cpad(int c) { return (c >> 4) * 17 + (c & 15); }

// exp(i*pi*x*m) with fp64 angle reduction, scaled
__device__ inline f2 phasef(float xv, float m, float scale) {
    double ang = (double)xv * (double)m;
    double r = ang - 2.0 * rint(ang * 0.5);
    float sn, cs;
    sincospif((float)r, &sn, &cs);
    return (f2){cs * scale, sn * scale};
}

// ---------------------------------------------------------------------------
// k_outer (unchanged best config: 0 conflicts, VGPR 92; (256,4) spills — R6)
// ---------------------------------------------------------------------------
__global__ __launch_bounds__(256, 2) void k_outer(const float* __restrict__ x,
                                                  const float* __restrict__ y,
                                                  float* __restrict__ pv,
                                                  float* __restrict__ pf,
                                                  int N, int cv, int cf)
{
    __shared__ f2 hs[PB][256];
    __shared__ float xs0[PB], xs1[PB], ys[PB];

    int bx = blockIdx.x;
    int t  = threadIdx.x;
    int ty = t >> 4, tx = t & 15;

    if (bx < cv) {
        int CP = (N + cv - 1) / cv;
        int n0 = bx * CP, n1 = min(N, n0 + CP);

        f2 acc[8][8];
        #pragma unroll
        for (int i = 0; i < 8; ++i)
            #pragma unroll
            for (int j = 0; j < 8; ++j) acc[i][j] = (f2){0.f, 0.f};

        for (int s = n0; s < n1; s += PB) {
            int cnt = min(PB, n1 - s);
            __syncthreads();
            if (t < cnt) {
                xs0[t] = x[2 * (s + t)];
                xs1[t] = x[2 * (s + t) + 1];
            }
            __syncthreads();
            for (int p = 0; p < cnt; ++p) {
                f2 g;
                if (t < 128)
                    g = (t == 127) ? (f2){0.f, 0.f} : phasef(xs0[p], (float)t - 63.f, 1.f);
                else {
                    int c = t - 128;
                    g = (c == 127) ? (f2){0.f, 0.f} : phasef(xs1[p], (float)c - 63.f, 1.f);
                }
                hs[p][t] = g;
            }
            __syncthreads();
            for (int p = 0; p < cnt; ++p) {
                f2 h1[8], h2[8], h2s[8];
                #pragma unroll
                for (int i = 0; i < 8; ++i) h1[i] = hs[p][ty * 8 + i];
                #pragma unroll
                for (int j = 0; j < 8; ++j) {
                    f2 b = hs[p][128 + tx + 16 * j];
                    h2[j] = b;
                    h2s[j] = (f2){-b.y, b.x};
                }
                #pragma unroll
                for (int i = 0; i < 8; ++i)
                    #pragma unroll
                    for (int j = 0; j < 8; ++j) {
                        acc[i][j] = acc[i][j] + f2s(h1[i].x) * h2[j];
                        acc[i][j] = acc[i][j] + f2s(h1[i].y) * h2s[j];
                    }
            }
        }
        __syncthreads();
        f2* out = (f2*)pv + (size_t)bx * 16384;
        #pragma unroll
        for (int i = 0; i < 8; ++i) {
            int a = ty * 8 + i;
            #pragma unroll
            for (int j = 0; j < 8; ++j)
                out[a * 128 + tx + 16 * j] = acc[i][j];
        }
    } else {
        int chunk = bx - cv;
        int CP = (N + cf - 1) / cf;
        int n0 = chunk * CP, n1 = min(N, n0 + CP);

        f2 acc[4][4];
        #pragma unroll
        for (int i = 0; i < 4; ++i)
            #pragma unroll
            for (int j = 0; j < 4; ++j) acc[i][j] = (f2){0.f, 0.f};

        for (int s = n0; s < n1; s += PB) {
            int cnt = min(PB, n1 - s);
            __syncthreads();
            if (t < cnt) {
                xs0[t] = x[2 * (s + t)];
                xs1[t] = x[2 * (s + t) + 1];
                ys[t]  = y[s + t];
            }
            __syncthreads();
            for (int p2 = 0; p2 < cnt; p2 += 2) {
                int p = p2 + (t >> 7);
                int c = t & 127;
                if (p < cnt) {
                    f2 g;
                    if (c < 64) g = phasef(xs0[p], (float)(32 - c), ys[p]);
                    else        g = phasef(xs1[p], (float)(32 - (c - 64)), 1.f);
                    hs[p][c] = g;
                }
            }
            __syncthreads();
            for (int p = 0; p < cnt; ++p) {
                f2 h1[4], h2[4], h2s[4];
                #pragma unroll
                for (int i = 0; i < 4; ++i) h1[i] = hs[p][ty * 4 + i];
                #pragma unroll
                for (int j = 0; j < 4; ++j) {
                    f2 b = hs[p][64 + tx + 16 * j];
                    h2[j] = b;
                    h2s[j] = (f2){-b.y, b.x};
                }
                #pragma unroll
                for (int i = 0; i < 4; ++i)
                    #pragma unroll
                    for (int j = 0; j < 4; ++j) {
                        acc[i][j] = acc[i][j] + f2s(h1[i].x) * h2[j];
                        acc[i][j] = acc[i][j] + f2s(h1[i].y) * h2s[j];
                    }
            }
        }
        __syncthreads();
        f2* out = (f2*)pf + (size_t)chunk * 4096;
        #pragma unroll
        for (int i = 0; i < 4; ++i) {
            int a = ty * 4 + i;
            #pragma unroll
            for (int j = 0; j < 4; ++j)
                out[a * 64 + tx + 16 * j] = acc[i][j];
        }
    }
}

// ---------------------------------------------------------------------------
// k_reduce (unchanged): partials -> circulant vcf (fp32) + rvec = ws*Fy (fp64)
// ---------------------------------------------------------------------------
__global__ __launch_bounds__(256) void k_reduce(const float* __restrict__ pv,
                                                const float* __restrict__ pf,
                                                const float* __restrict__ wsv,
                                                float* __restrict__ vcf,
                                                double2* __restrict__ rvec,
                                                int cv, int cf)
{
    int id = blockIdx.x * 256 + threadIdx.x;
    if (id < 131072) {
        int e = id >> 3, sl = id & 7;
        int q1 = e >> 7, q2 = e & 127;
        int a = (q1 + 63) & 127, b = (q2 + 63) & 127;
        int cn = cv >> 3;
        const float* src = pv + (size_t)(a * 128 + b) * 2
                              + (size_t)(sl * cn) * 32768;
        float sx = 0.f, sy = 0.f;
        for (int c = 0; c < cn; ++c) { sx += src[0]; sy += src[1]; src += 32768; }
        atomicAdd(&vcf[e * 2], sx);
        atomicAdd(&vcf[e * 2 + 1], sy);
    } else {
        int e = id - 131072;
        const float* s2p = pf + (size_t)e * 2;
        double fx = 0.0, fy2 = 0.0;
        for (int c = 0; c < cf; ++c) { fx += (double)s2p[0]; fy2 += (double)s2p[1]; s2p += 8192; }
        double w = (double)wsv[e];
        rvec[e] = make_double2(w * fx, w * fy2);
    }
}

// ---------------------------------------------------------------------------
// Fused-stage FFT passes, STATIC register indexing only.
// Z[r*RS + cpad(c)], RS=137. tw[t] = exp(-i*pi*t/64) = W_128^t.
// ---------------------------------------------------------------------------
__device__ inline void bflyA_fwd(f2* L, const f2* tw, int b) {
    #pragma unroll
    for (int s = 0; s < 4; ++s) {                    // h=64
        f2 u0 = L[s], v0 = L[s + 4];
        L[s] = u0 + v0;
        L[s + 4] = cmulf(u0 - v0, tw[b + 16 * s]);
    }
    const int ss[4] = {0, 1, 4, 5};
    #pragma unroll
    for (int q = 0; q < 4; ++q) {                    // h=32
        int s = ss[q];
        f2 u0 = L[s], v0 = L[s + 2];
        L[s] = u0 + v0;
        L[s + 2] = cmulf(u0 - v0, tw[2 * b + 32 * (s & 1)]);
    }
    #pragma unroll
    for (int s = 0; s < 8; s += 2) {                 // h=16
        f2 u0 = L[s], v0 = L[s + 1];
        L[s] = u0 + v0;
        L[s + 1] = cmulf(u0 - v0, tw[4 * b]);
    }
}
__device__ inline void bflyA_inv(f2* L, const f2* tw, int b) {
    #pragma unroll
    for (int s = 0; s < 8; s += 2) {                 // h=16
        f2 u0 = L[s];
        f2 vw = cmulcf(L[s + 1], tw[4 * b]);
        L[s] = u0 + vw; L[s + 1] = u0 - vw;
    }
    const int ss[4] = {0, 1, 4, 5};
    #pragma unroll
    for (int q = 0; q < 4; ++q) {                    // h=32
        int s = ss[q];
        f2 u0 = L[s];
        f2 vw = cmulcf(L[s + 2], tw[2 * b + 32 * (s & 1)]);
        L[s] = u0 + vw; L[s + 2] = u0 - vw;
    }
    #pragma unroll
    for (int s = 0; s < 4; ++s) {                    // h=64
        f2 u0 = L[s];
        f2 vw = cmulcf(L[s + 4], tw[b + 16 * s]);
        L[s] = u0 + vw; L[s + 4] = u0 - vw;
    }
}
__device__ inline void bfly16_fwd(f2* M, const f2* tw) {
    #pragma unroll
    for (int s = 0; s < 8; ++s) {                    // h=8
        f2 u0 = M[s], v0 = M[s + 8];
        M[s] = u0 + v0;
        M[s + 8] = cmulf(u0 - v0, tw[8 * s]);
    }
    #pragma unroll
    for (int q = 0; q < 8; ++q) {                    // h=4
        int s = (q & 3) + 8 * (q >> 2);
        f2 u0 = M[s], v0 = M[s + 4];
        M[s] = u0 + v0;
        M[s + 4] = cmulf(u0 - v0, tw[16 * (s & 3)]);
    }
    #pragma unroll
    for (int q = 0; q < 8; ++q) {                    // h=2
        int s = (q & 1) + 4 * (q >> 1);
        f2 u0 = M[s], v0 = M[s + 2];
        M[s] = u0 + v0;
        M[s + 2] = cmulf(u0 - v0, tw[32 * (s & 1)]);
    }
    #pragma unroll
    for (int s = 0; s < 16; s += 2) {                // h=1
        f2 u0 = M[s], v0 = M[s + 1];
        M[s] = u0 + v0; M[s + 1] = u0 - v0;
    }
}
__device__ inline void bfly16_inv(f2* M, const f2* tw) {
    #pragma unroll
    for (int s = 0; s < 16; s += 2) {                // h=1
        f2 u0 = M[s], v0 = M[s + 1];
        M[s] = u0 + v0; M[s + 1] = u0 - v0;
    }
    #pragma unroll
    for (int q = 0; q < 8; ++q) {                    // h=2
        int s = (q & 1) + 4 * (q >> 1);
        f2 u0 = M[s];
        f2 vw = cmulcf(M[s + 2], tw[32 * (s & 1)]);
        M[s] = u0 + vw; M[s + 2] = u0 - vw;
    }
    #pragma unroll
    for (int q = 0; q < 8; ++q) {                    // h=4
        int s = (q & 3) + 8 * (q >> 2);
        f2 u0 = M[s];
        f2 vw = cmulcf(M[s + 4], tw[16 * (s & 3)]);
        M[s] = u0 + vw; M[s + 4] = u0 - vw;
    }
    #pragma unroll
    for (int s = 0; s < 8; ++s) {                    // h=8
        f2 u0 = M[s];
        f2 vw = cmulcf(M[s + 8], tw[8 * s]);
        M[s] = u0 + vw; M[s + 8] = u0 - vw;
    }
}

__device__ inline void f_rowA(f2* Z, const f2* tw, int tid, int nrows, bool zup) {
    for (int u = tid; u < nrows * 16; u += 1024) {
        int r = u >> 4, b = u & 15;
        f2* row = Z + r * RS;
        f2 L[8];
        #pragma unroll
        for (int s = 0; s < 4; ++s) L[s] = row[17 * s + b];
        if (zup) {
            #pragma unroll
            for (int s = 4; s < 8; ++s) L[s] = (f2){0.f, 0.f};
        } else {
            #pragma unroll
            for (int s = 4; s < 8; ++s) L[s] = row[17 * s + b];
        }
        bflyA_fwd(L, tw, b);
        #pragma unroll
        for (int s = 0; s < 8; ++s) row[17 * s + b] = L[s];
    }
}
__device__ inline void i_rowA(f2* Z, const f2* tw, int tid, int nrows) {
    for (int u = tid; u < nrows * 16; u += 1024) {
        int r = u >> 4, b = u & 15;
        f2* row = Z + r * RS;
        f2 L[8];
        #pragma unroll
        for (int s = 0; s < 8; ++s) L[s] = row[17 * s + b];
        bflyA_inv(L, tw, b);
        #pragma unroll
        for (int s = 0; s < 8; ++s) row[17 * s + b] = L[s];
    }
}
__device__ inline void f_rowB(f2* Z, const f2* tw, int tid, int nrows) {
    for (int u = tid; u < nrows * 8; u += 1024) {
        int r = u >> 3, g = u & 7;
        f2* blk = Z + r * RS + g * 17;
        f2 M[16];
        #pragma unroll
        for (int s = 0; s < 16; ++s) M[s] = blk[s];
        bfly16_fwd(M, tw);
        #pragma unroll
        for (int s = 0; s < 16; ++s) blk[s] = M[s];
    }
}
__device__ inline void i_rowB(f2* Z, const f2* tw, int tid, int nrows) {
    for (int u = tid; u < nrows * 8; u += 1024) {
        int r = u >> 3, g = u & 7;
        f2* blk = Z + r * RS + g * 17;
        f2 M[16];
        #pragma unroll
        for (int s = 0; s < 16; ++s) M[s] = blk[s];
        bfly16_inv(M, tw);
        #pragma unroll
        for (int s = 0; s < 16; ++s) blk[s] = M[s];
    }
}
__device__ inline void f_colA(f2* Z, const f2* tw, int tid, bool zup) {
    for (int u = tid; u < 2048; u += 1024) {
        int c = u >> 4, b = u & 15;
        int cp = cpad(c);
        f2 L[8];
        #pragma unroll
        for (int s = 0; s < 4; ++s) L[s] = Z[(b + 16 * s) * RS + cp];
        if (zup) {
            #pragma unroll
            for (int s = 4; s < 8; ++s) L[s] = (f2){0.f, 0.f};
        } else {
            #pragma unroll
            for (int s = 4; s < 8; ++s) L[s] = Z[(b + 16 * s) * RS + cp];
        }
        bflyA_fwd(L, tw, b);
        #pragma unroll
        for (int s = 0; s < 8; ++s) Z[(b + 16 * s) * RS + cp] = L[s];
    }
}
__device__ inline void i_colA(f2* Z, const f2* tw, int tid) {
    for (int u = tid; u < 2048; u += 1024) {
        int c = u >> 4, b = u & 15;
        int cp = cpad(c);
        f2 L[8];
        #pragma unroll
        for (int s = 0; s < 8; ++s) L[s] = Z[(b + 16 * s) * RS + cp];
        bflyA_inv(L, tw, b);
        #pragma unroll
        for (int s = 0; s < 8; ++s) Z[(b + 16 * s) * RS + cp] = L[s];
    }
}
// colB: lanes span 64 columns (c = tid&127) so banks vary across a wave.
__device__ inline void f_colB(f2* Z, const f2* tw, int tid) {        // setup
    int c = tid & 127, g = tid >> 7;
    f2* col = Z + g * 16 * RS + cpad(c);
    f2 M[16];
    #pragma unroll
    for (int s = 0; s < 16; ++s) M[s] = col[s * RS];
    bfly16_fwd(M, tw);
    #pragma unroll
    for (int s = 0; s < 16; ++s) col[s * RS] = M[s];
}
__device__ inline void it_colB(f2* Z, const f2* tw, const f2* Vfg, int tid) {
    int c = tid & 127, g = tid >> 7;
    f2* col = Z + g * 16 * RS + cpad(c);
    const f2* vf = Vfg + g * 16 * 128 + c;
    f2 M[16];
    #pragma unroll
    for (int s = 0; s < 16; ++s) M[s] = col[s * RS];
    bfly16_fwd(M, tw);
    #pragma unroll
    for (int s = 0; s < 16; ++s) M[s] = cmulf(M[s], vf[s * 128]);
    bfly16_inv(M, tw);
    #pragma unroll
    for (int s = 0; s < 16; ++s) col[s * RS] = M[s];
}

// One-barrier reduces (buffer reuse separated by the many pass barriers).
__device__ inline double blk_reduce(double v, double* red, int wid, int m) {
    #pragma unroll
    for (int off = 32; off > 0; off >>= 1) v += __shfl_down(v, off);
    if (m == 0) red[wid] = v;
    __syncthreads();
    double s = 0.0;
    #pragma unroll
    for (int i = 0; i < 16; ++i) s += red[i];
    return s;
}
__device__ inline void blk_reduce3(double& a, double& b, double& c,
                                   double (*red)[3], int wid, int m) {
    #pragma unroll
    for (int off = 32; off > 0; off >>= 1) {
        a += __shfl_down(a, off);
        b += __shfl_down(b, off);
        c += __shfl_down(c, off);
    }
    if (m == 0) { red[wid][0] = a; red[wid][1] = b; red[wid][2] = c; }
    __syncthreads();
    double sa = 0.0, sb = 0.0, sc = 0.0;
    #pragma unroll
    for (int i = 0; i < 16; ++i) { sa += red[i][0]; sb += red[i][1]; sc += red[i][2]; }
    a = sa; b = sb; c = sc;
}

// ---------------------------------------------------------------------------
// k_cg_solve: Vf setup + 50 CG iterations in one launch (one block).
// ---------------------------------------------------------------------------
__global__ __launch_bounds__(1024, 4) void k_cg_solve(
        const float* __restrict__ vcf, float* __restrict__ Vf,
        const double2* __restrict__ rvec, const float* __restrict__ wsv,
        const float* __restrict__ sig2, double2* __restrict__ xg,
        float* __restrict__ alg)
{
    __shared__ f2 Z[128 * RS];
    __shared__ f2 tw[64];
    __shared__ double red1[16];
    __shared__ double red3[16][3];

    int tid = threadIdx.x;
    int wid = tid >> 6, m = tid & 63;

    if (tid < 64) {
        float sn, cs;
        sincospif(-(float)tid / 64.f, &sn, &cs);
        tw[tid] = (f2){cs, sn};
    }
    __syncthreads();

    // ---- Vf setup (forward transform of vc, scrambled order)
    for (int i = tid; i < 16384; i += 1024)
        Z[(i >> 7) * RS + cpad(i & 127)] = ((const f2*)vcf)[i];
    __syncthreads();
    f_rowA(Z, tw, tid, 128, false); __syncthreads();
    f_rowB(Z, tw, tid, 128);        __syncthreads();
    f_colA(Z, tw, tid, false);      __syncthreads();
    f_colB(Z, tw, tid);             __syncthreads();
    for (int i = tid; i < 16384; i += 1024)
        ((f2*)Vf)[i] = Z[(i >> 7) * RS + cpad(i & 127)];
    __syncthreads();

    // ---- CG state (p, r in regs; x in global); scatter z0 = ws*p0
    double2 pR[4], rR[4];
    float wsr[4];
    int zix[4];
    double rzp = 0.0;
    #pragma unroll
    for (int s = 0; s < 4; ++s) {
        int e = tid + (s << 10);
        double2 bv = rvec[e];
        pR[s] = bv; rR[s] = bv;
        wsr[s] = wsv[e];
        zix[s] = (e >> 6) * RS + cpad(e & 63);
        xg[e] = make_double2(0.0, 0.0);
        Z[zix[s]] = (f2){(float)((double)wsr[s] * bv.x),
                         (float)((double)wsr[s] * bv.y)};
        rzp += bv.x * bv.x + bv.y * bv.y;
    }
    double rz = blk_reduce(rzp, red1, wid, m);   // barrier also orders z0 scatter
    double s2 = (double)sig2[0];
    const double inv16384 = 1.0 / 16384.0;

    for (int it = 0; it < 50; ++it) {
        f_rowA(Z, tw, tid, 64, true);           __syncthreads();
        f_rowB(Z, tw, tid, 64);                 __syncthreads();
        f_colA(Z, tw, tid, true);               __syncthreads();
        it_colB(Z, tw, (const f2*)Vf, tid);     __syncthreads();
        i_colA(Z, tw, tid);                     __syncthreads();
        i_rowB(Z, tw, tid, 64);                 __syncthreads();
        i_rowA(Z, tw, tid, 64);                 __syncthreads();

        // Ap, 3 dots in one reduce
        f2 tz[4];
        double d1 = 0.0, d2 = 0.0, d3 = 0.0;   // <p,Ap>, <r,Ap>, <Ap,Ap>
        #pragma unroll
        for (int s = 0; s < 4; ++s) {
            tz[s] = Z[zix[s]];
            double apx = (double)wsr[s] * (double)tz[s].x * inv16384 + s2 * pR[s].x;
            double apy = (double)wsr[s] * (double)tz[s].y * inv16384 + s2 * pR[s].y;
            d1 += pR[s].x * apx + pR[s].y * apy;
            d2 += rR[s].x * apx + rR[s].y * apy;
            d3 += apx * apx + apy * apy;
        }
        blk_reduce3(d1, d2, d3, red3, wid, m);
        double alpha = rz / (d1 + 1e-30);
        double rzn = fma(alpha, fma(alpha, d3, -2.0 * d2), rz);
        double beta = rzn / (rz + 1e-30);
        rz = rzn;

        if (it < 49) {
            // update x,r,p and scatter z = ws*p_new (Z reads done pre-reduce)
            #pragma unroll
            for (int s = 0; s < 4; ++s) {
                int e = tid + (s << 10);
                double apx = (double)wsr[s] * (double)tz[s].x * inv16384 + s2 * pR[s].x;
                double apy = (double)wsr[s] * (double)tz[s].y * inv16384 + s2 * pR[s].y;
                double2 xv = xg[e];
                xv.x += alpha * pR[s].x; xv.y += alpha * pR[s].y;
                xg[e] = xv;
                rR[s].x -= alpha * apx; rR[s].y -= alpha * apy;
                pR[s].x = rR[s].x + beta * pR[s].x;
                pR[s].y = rR[s].y + beta * pR[s].y;
                Z[zix[s]] = (f2){(float)((double)wsr[s] * pR[s].x),
                                 (float)((double)wsr[s] * pR[s].y)};
            }
            __syncthreads();
        } else {
            // final: x_50 = x_49 + alpha*p; emit al = ws*x_50
            #pragma unroll
            for (int s = 0; s < 4; ++s) {
                int e = tid + (s << 10);
                double2 xv = xg[e];
                xv.x += alpha * pR[s].x; xv.y += alpha * pR[s].y;
                ((f2*)alg)[e] = (f2){(float)((double)wsr[s] * xv.x),
                                     (float)((double)wsr[s] * xv.y)};
            }
        }
    }
}

// ---------------------------------------------------------------------------
// k_eval (unchanged)
// ---------------------------------------------------------------------------
__global__ __launch_bounds__(64) void k_eval(const float* __restrict__ xnew,
                                             const float* __restrict__ alg,
                                             float* __restrict__ out, int B)
{
    __shared__ float2 al[4096];
    int t = threadIdx.x;
    int b = blockIdx.x * 64 + t;
    for (int i = t; i < 4096; i += 64) {
        f2 v = ((const f2*)alg)[i];
        al[i] = make_float2(v.x, v.y);
    }
    float x0 = 0.f, x1 = 0.f;
    if (b < B) { x0 = xnew[2 * b]; x1 = xnew[2 * b + 1]; }
    __syncthreads();
    double2 wstep; { double sn, cs; sincospi((double)x1, &sn, &cs); wstep = make_double2(cs, sn); }
    double mu = 0.0;
    for (int jg = 0; jg < 4; ++jg) {
        float2 tacc[16];
        for (int q = 0; q < 16; ++q) tacc[q] = make_float2(0.f, 0.f);
        double2 e2; { double sn, cs; sincospi(-32.0 * (double)x1, &sn, &cs); e2 = make_double2(cs, sn); }
        for (int k = 0; k < 64; ++k) {
            float2 e2f = make_float2((float)e2.x, (float)e2.y);
            for (int q = 0; q < 16; ++q) {
                int j = jg * 16 + q;
                float2 a = al[j * 64 + k];
                tacc[q].x += a.x * e2f.x - a.y * e2f.y;
                tacc[q].y += a.x * e2f.y + a.y * e2f.x;
            }
            e2 = make_double2(e2.x * wstep.x - e2.y * wstep.y,
                              e2.x * wstep.y + e2.y * wstep.x);
        }
        for (int q = 0; q < 16; ++q) {
            int j = jg * 16 + q;
            double sn, cs;
            sincospi((double)x0 * (double)(j - 32), &sn, &cs);
            mu += cs * (double)tacc[q].x - sn * (double)tacc[q].y;
        }
    }
    if (b < B) out[b] = (float)mu;
}

// ---------------------------------------------------------------------------

extern "C" void kernel_launch(void* const* d_in, const int* in_sizes, int n_in,
                              void* d_out, int out_size, void* d_ws, size_t ws_size,
                              hipStream_t stream)
{
    const float* x    = (const float*)d_in[0];
    const float* y    = (const float*)d_in[1];
    const float* xnew = (const float*)d_in[2];
    const float* wsv  = (const float*)d_in[3];
    const float* sig2 = (const float*)d_in[4];
    int N = in_sizes[1];
    int B = in_sizes[2] / 2;

    char* base = (char*)d_ws;
    size_t o = 0;
    float*   vcf  = (float*)(base + o);   o += 131072;   // 128x128 circulant vc (fp32)
    float*   Vf   = (float*)(base + o);   o += 131072;   // scrambled 2D FFT of vc
    double2* rvec = (double2*)(base + o); o += 65536;    // b = ws*Fy (fp64)
    double2* xg   = (double2*)(base + o); o += 65536;    // CG solution x (fp64)
    float*   alg  = (float*)(base + o);   o += 32768;    // ws*x_50 (fp32 complex)
    size_t avail = (ws_size > o) ? ws_size - o : 0;
    int cv = (int)(avail / 139264);                      // 128KB v + 8KB fy per unit
    if (cv > 384) cv = 384;
    if (cv < 16) cv = 16;
    cv &= ~15;                                           // cv%8==0, cf%4==0
    int cf = cv / 4;
    float* pv = (float*)(base + o); o += (size_t)cv * 131072;
    float* pf = (float*)(base + o);

    hipMemsetAsync(vcf, 0, 131072, stream);              // fp32 atomic target

    k_outer<<<cv + cf, 256, 0, stream>>>(x, y, pv, pf, N, cv, cf);
    k_reduce<<<528, 256, 0, stream>>>(pv, pf, wsv, vcf, rvec, cv, cf);
    k_cg_solve<<<1, 1024, 0, stream>>>(vcf, Vf, rvec, wsv, sig2, xg, alg);
    k_eval<<<(B + 63) / 64, 64, 0, stream>>>(xnew, alg, (float*)d_out, B);
}

// Round 13
// 1459.884 us; speedup vs baseline: 1.0525x; 1.0525x over previous
//
#include <hip/hip_runtime.h>
#include <math.h>

// ---------------------------------------------------------------------------
// GP posterior mean:
//   k_outer : separable NUFFT outer products, fp32 atomic-free partials.
//             cv cap 768 (R12: grid 480 was the occupancy binder — LDS/VGPR
//             allow 4 blocks/CU but only ~2 were resident).
//   k_reduce: partials -> fp32 circulant table vcf + fp64 rhs b.
//   k_cg_solve: R11-exact (958 us verified). ONE launch, ONE 1024-thread
//     block; 50 CG iterations, in-LDS 128x128 FFT conv, fused stages, STATIC
//     reg indexing (R10: dynamic idx -> scratch), pad-17 layout.
//     R12 lesson: kernel is latency/barrier-bound — pk-cmul + fused reduce3
//     CUT VALUBusy but RAISED dur (958->1032). Keep scalar cmul + 2 reduces.
//   k_eval  : posterior mean at test points from al = ws*x_50.
// ---------------------------------------------------------------------------

typedef float f2 __attribute__((ext_vector_type(2)));
#define PB 16
#define RS 137          // Z row stride in f2 (8 blocks x 17)

__device__ inline f2 f2s(float s) { return (f2){s, s}; }
__device__ inline f2 cmulf(f2 a, f2 b) {   // a*b
    return (f2){a.x * b.x - a.y * b.y, a.x * b.y + a.y * b.x};
}
__device__ inline f2 cmulcf(f2 a, f2 b) {  // a*conj(b)
    return (f2){a.x * b.x + a.y * b.y, a.y * b.x - a.x * b.y};
}
__device__ inline int cpad(int c) { return (c >> 4) * 17 + (c & 15); }

// exp(i*pi*x*m) with fp64 angle reduction, scaled
__device__ inline f2 phasef(float xv, float m, float scale) {
    double ang = (double)xv * (double)m;
    double r = ang - 2.0 * rint(ang * 0.5);
    float sn, cs;
    sincospif((float)r, &sn, &cs);
    return (f2){cs * scale, sn * scale};
}

// ---------------------------------------------------------------------------
// k_outer (code unchanged — best-known config; (256,4) spills, R6)
// ---------------------------------------------------------------------------
__global__ __launch_bounds__(256, 2) void k_outer(const float* __restrict__ x,
                                                  const float* __restrict__ y,
                                                  float* __restrict__ pv,
                                                  float* __restrict__ pf,
                                                  int N, int cv, int cf)
{
    __shared__ f2 hs[PB][256];
    __shared__ float xs0[PB], xs1[PB], ys[PB];

    int bx = blockIdx.x;
    int t  = threadIdx.x;
    int ty = t >> 4, tx = t & 15;

    if (bx < cv) {
        int CP = (N + cv - 1) / cv;
        int n0 = bx * CP, n1 = min(N, n0 + CP);

        f2 acc[8][8];
        #pragma unroll
        for (int i = 0; i < 8; ++i)
            #pragma unroll
            for (int j = 0; j < 8; ++j) acc[i][j] = (f2){0.f, 0.f};

        for (int s = n0; s < n1; s += PB) {
            int cnt = min(PB, n1 - s);
            __syncthreads();
            if (t < cnt) {
                xs0[t] = x[2 * (s + t)];
                xs1[t] = x[2 * (s + t) + 1];
            }
            __syncthreads();
            for (int p = 0; p < cnt; ++p) {
                f2 g;
                if (t < 128)
                    g = (t == 127) ? (f2){0.f, 0.f} : phasef(xs0[p], (float)t - 63.f, 1.f);
                else {
                    int c = t - 128;
                    g = (c == 127) ? (f2){0.f, 0.f} : phasef(xs1[p], (float)c - 63.f, 1.f);
                }
                hs[p][t] = g;
            }
            __syncthreads();
            for (int p = 0; p < cnt; ++p) {
                f2 h1[8], h2[8], h2s[8];
                #pragma unroll
                for (int i = 0; i < 8; ++i) h1[i] = hs[p][ty * 8 + i];
                #pragma unroll
                for (int j = 0; j < 8; ++j) {
                    f2 b = hs[p][128 + tx + 16 * j];
                    h2[j] = b;
                    h2s[j] = (f2){-b.y, b.x};
                }
                #pragma unroll
                for (int i = 0; i < 8; ++i)
                    #pragma unroll
                    for (int j = 0; j < 8; ++j) {
                        acc[i][j] = acc[i][j] + f2s(h1[i].x) * h2[j];
                        acc[i][j] = acc[i][j] + f2s(h1[i].y) * h2s[j];
                    }
            }
        }
        __syncthreads();
        f2* out = (f2*)pv + (size_t)bx * 16384;
        #pragma unroll
        for (int i = 0; i < 8; ++i) {
            int a = ty * 8 + i;
            #pragma unroll
            for (int j = 0; j < 8; ++j)
                out[a * 128 + tx + 16 * j] = acc[i][j];
        }
    } else {
        int chunk = bx - cv;
        int CP = (N + cf - 1) / cf;
        int n0 = chunk * CP, n1 = min(N, n0 + CP);

        f2 acc[4][4];
        #pragma unroll
        for (int i = 0; i < 4; ++i)
            #pragma unroll
            for (int j = 0; j < 4; ++j) acc[i][j] = (f2){0.f, 0.f};

        for (int s = n0; s < n1; s += PB) {
            int cnt = min(PB, n1 - s);
            __syncthreads();
            if (t < cnt) {
                xs0[t] = x[2 * (s + t)];
                xs1[t] = x[2 * (s + t) + 1];
                ys[t]  = y[s + t];
            }
            __syncthreads();
            for (int p2 = 0; p2 < cnt; p2 += 2) {
                int p = p2 + (t >> 7);
                int c = t & 127;
                if (p < cnt) {
                    f2 g;
                    if (c < 64) g = phasef(xs0[p], (float)(32 - c), ys[p]);
                    else        g = phasef(xs1[p], (float)(32 - (c - 64)), 1.f);
                    hs[p][c] = g;
                }
            }
            __syncthreads();
            for (int p = 0; p < cnt; ++p) {
                f2 h1[4], h2[4], h2s[4];
                #pragma unroll
                for (int i = 0; i < 4; ++i) h1[i] = hs[p][ty * 4 + i];
                #pragma unroll
                for (int j = 0; j < 4; ++j) {
                    f2 b = hs[p][64 + tx + 16 * j];
                    h2[j] = b;
                    h2s[j] = (f2){-b.y, b.x};
                }
                #pragma unroll
                for (int i = 0; i < 4; ++i)
                    #pragma unroll
                    for (int j = 0; j < 4; ++j) {
                        acc[i][j] = acc[i][j] + f2s(h1[i].x) * h2[j];
                        acc[i][j] = acc[i][j] + f2s(h1[i].y) * h2s[j];
                    }
            }
        }
        __syncthreads();
        f2* out = (f2*)pf + (size_t)chunk * 4096;
        #pragma unroll
        for (int i = 0; i < 4; ++i) {
            int a = ty * 4 + i;
            #pragma unroll
            for (int j = 0; j < 4; ++j)
                out[a * 64 + tx + 16 * j] = acc[i][j];
        }
    }
}

// ---------------------------------------------------------------------------
// k_reduce (unchanged): partials -> circulant vcf (fp32) + rvec = ws*Fy (fp64)
// ---------------------------------------------------------------------------
__global__ __launch_bounds__(256) void k_reduce(const float* __restrict__ pv,
                                                const float* __restrict__ pf,
                                                const float* __restrict__ wsv,
                                                float* __restrict__ vcf,
                                                double2* __restrict__ rvec,
                                                int cv, int cf)
{
    int id = blockIdx.x * 256 + threadIdx.x;
    if (id < 131072) {
        int e = id >> 3, sl = id & 7;
        int q1 = e >> 7, q2 = e & 127;
        int a = (q1 + 63) & 127, b = (q2 + 63) & 127;
        int cn = cv >> 3;
        const float* src = pv + (size_t)(a * 128 + b) * 2
                              + (size_t)(sl * cn) * 32768;
        float sx = 0.f, sy = 0.f;
        for (int c = 0; c < cn; ++c) { sx += src[0]; sy += src[1]; src += 32768; }
        atomicAdd(&vcf[e * 2], sx);
        atomicAdd(&vcf[e * 2 + 1], sy);
    } else {
        int e = id - 131072;
        const float* s2p = pf + (size_t)e * 2;
        double fx = 0.0, fy2 = 0.0;
        for (int c = 0; c < cf; ++c) { fx += (double)s2p[0]; fy2 += (double)s2p[1]; s2p += 8192; }
        double w = (double)wsv[e];
        rvec[e] = make_double2(w * fx, w * fy2);
    }
}

// ---------------------------------------------------------------------------
// Fused-stage FFT passes, STATIC register indexing only (R11-exact).
// Z[r*RS + cpad(c)], RS=137. tw[t] = exp(-i*pi*t/64) = W_128^t.
// ---------------------------------------------------------------------------
__device__ inline void bflyA_fwd(f2* L, const f2* tw, int b) {
    #pragma unroll
    for (int s = 0; s < 4; ++s) {                    // h=64
        f2 u0 = L[s], v0 = L[s + 4];
        L[s] = u0 + v0;
        L[s + 4] = cmulf(u0 - v0, tw[b + 16 * s]);
    }
    const int ss[4] = {0, 1, 4, 5};
    #pragma unroll
    for (int q = 0; q < 4; ++q) {                    // h=32
        int s = ss[q];
        f2 u0 = L[s], v0 = L[s + 2];
        L[s] = u0 + v0;
        L[s + 2] = cmulf(u0 - v0, tw[2 * b + 32 * (s & 1)]);
    }
    #pragma unroll
    for (int s = 0; s < 8; s += 2) {                 // h=16
        f2 u0 = L[s], v0 = L[s + 1];
        L[s] = u0 + v0;
        L[s + 1] = cmulf(u0 - v0, tw[4 * b]);
    }
}
__device__ inline void bflyA_inv(f2* L, const f2* tw, int b) {
    #pragma unroll
    for (int s = 0; s < 8; s += 2) {                 // h=16
        f2 u0 = L[s];
        f2 vw = cmulcf(L[s + 1], tw[4 * b]);
        L[s] = u0 + vw; L[s + 1] = u0 - vw;
    }
    const int ss[4] = {0, 1, 4, 5};
    #pragma unroll
    for (int q = 0; q < 4; ++q) {                    // h=32
        int s = ss[q];
        f2 u0 = L[s];
        f2 vw = cmulcf(L[s + 2], tw[2 * b + 32 * (s & 1)]);
        L[s] = u0 + vw; L[s + 2] = u0 - vw;
    }
    #pragma unroll
    for (int s = 0; s < 4; ++s) {                    // h=64
        f2 u0 = L[s];
        f2 vw = cmulcf(L[s + 4], tw[b + 16 * s]);
        L[s] = u0 + vw; L[s + 4] = u0 - vw;
    }
}
__device__ inline void bfly16_fwd(f2* M, const f2* tw) {
    #pragma unroll
    for (int s = 0; s < 8; ++s) {                    // h=8
        f2 u0 = M[s], v0 = M[s + 8];
        M[s] = u0 + v0;
        M[s + 8] = cmulf(u0 - v0, tw[8 * s]);
    }
    #pragma unroll
    for (int q = 0; q < 8; ++q) {                    // h=4
        int s = (q & 3) + 8 * (q >> 2);
        f2 u0 = M[s], v0 = M[s + 4];
        M[s] = u0 + v0;
        M[s + 4] = cmulf(u0 - v0, tw[16 * (s & 3)]);
    }
    #pragma unroll
    for (int q = 0; q < 8; ++q) {                    // h=2
        int s = (q & 1) + 4 * (q >> 1);
        f2 u0 = M[s], v0 = M[s + 2];
        M[s] = u0 + v0;
        M[s + 2] = cmulf(u0 - v0, tw[32 * (s & 1)]);
    }
    #pragma unroll
    for (int s = 0; s < 16; s += 2) {                // h=1
        f2 u0 = M[s], v0 = M[s + 1];
        M[s] = u0 + v0; M[s + 1] = u0 - v0;
    }
}
__device__ inline void bfly16_inv(f2* M, const f2* tw) {
    #pragma unroll
    for (int s = 0; s < 16; s += 2) {                // h=1
        f2 u0 = M[s], v0 = M[s + 1];
        M[s] = u0 + v0; M[s + 1] = u0 - v0;
    }
    #pragma unroll
    for (int q = 0; q < 8; ++q) {                    // h=2
        int s = (q & 1) + 4 * (q >> 1);
        f2 u0 = M[s];
        f2 vw = cmulcf(M[s + 2], tw[32 * (s & 1)]);
        M[s] = u0 + vw; M[s + 2] = u0 - vw;
    }
    #pragma unroll
    for (int q = 0; q < 8; ++q) {                    // h=4
        int s = (q & 3) + 8 * (q >> 2);
        f2 u0 = M[s];
        f2 vw = cmulcf(M[s + 4], tw[16 * (s & 3)]);
        M[s] = u0 + vw; M[s + 4] = u0 - vw;
    }
    #pragma unroll
    for (int s = 0; s < 8; ++s) {                    // h=8
        f2 u0 = M[s];
        f2 vw = cmulcf(M[s + 8], tw[8 * s]);
        M[s] = u0 + vw; M[s + 8] = u0 - vw;
    }
}

__device__ inline void f_rowA(f2* Z, const f2* tw, int tid, int nrows, bool zup) {
    for (int u = tid; u < nrows * 16; u += 1024) {
        int r = u >> 4, b = u & 15;
        f2* row = Z + r * RS;
        f2 L[8];
        #pragma unroll
        for (int s = 0; s < 4; ++s) L[s] = row[17 * s + b];
        if (zup) {
            #pragma unroll
            for (int s = 4; s < 8; ++s) L[s] = (f2){0.f, 0.f};
        } else {
            #pragma unroll
            for (int s = 4; s < 8; ++s) L[s] = row[17 * s + b];
        }
        bflyA_fwd(L, tw, b);
        #pragma unroll
        for (int s = 0; s < 8; ++s) row[17 * s + b] = L[s];
    }
}
__device__ inline void i_rowA(f2* Z, const f2* tw, int tid, int nrows) {
    for (int u = tid; u < nrows * 16; u += 1024) {
        int r = u >> 4, b = u & 15;
        f2* row = Z + r * RS;
        f2 L[8];
        #pragma unroll
        for (int s = 0; s < 8; ++s) L[s] = row[17 * s + b];
        bflyA_inv(L, tw, b);
        #pragma unroll
        for (int s = 0; s < 8; ++s) row[17 * s + b] = L[s];
    }
}
__device__ inline void f_rowB(f2* Z, const f2* tw, int tid, int nrows) {
    for (int u = tid; u < nrows * 8; u += 1024) {
        int r = u >> 3, g = u & 7;
        f2* blk = Z + r * RS + g * 17;
        f2 M[16];
        #pragma unroll
        for (int s = 0; s < 16; ++s) M[s] = blk[s];
        bfly16_fwd(M, tw);
        #pragma unroll
        for (int s = 0; s < 16; ++s) blk[s] = M[s];
    }
}
__device__ inline void i_rowB(f2* Z, const f2* tw, int tid, int nrows) {
    for (int u = tid; u < nrows * 8; u += 1024) {
        int r = u >> 3, g = u & 7;
        f2* blk = Z + r * RS + g * 17;
        f2 M[16];
        #pragma unroll
        for (int s = 0; s < 16; ++s) M[s] = blk[s];
        bfly16_inv(M, tw);
        #pragma unroll
        for (int s = 0; s < 16; ++s) blk[s] = M[s];
    }
}
__device__ inline void f_colA(f2* Z, const f2* tw, int tid, bool zup) {
    for (int u = tid; u < 2048; u += 1024) {
        int c = u >> 4, b = u & 15;
        int cp = cpad(c);
        f2 L[8];
        #pragma unroll
        for (int s = 0; s < 4; ++s) L[s] = Z[(b + 16 * s) * RS + cp];
        if (zup) {
            #pragma unroll
            for (int s = 4; s < 8; ++s) L[s] = (f2){0.f, 0.f};
        } else {
            #pragma unroll
            for (int s = 4; s < 8; ++s) L[s] = Z[(b + 16 * s) * RS + cp];
        }
        bflyA_fwd(L, tw, b);
        #pragma unroll
        for (int s = 0; s < 8; ++s) Z[(b + 16 * s) * RS + cp] = L[s];
    }
}
__device__ inline void i_colA(f2* Z, const f2* tw, int tid) {
    for (int u = tid; u < 2048; u += 1024) {
        int c = u >> 4, b = u & 15;
        int cp = cpad(c);
        f2 L[8];
        #pragma unroll
        for (int s = 0; s < 8; ++s) L[s] = Z[(b + 16 * s) * RS + cp];
        bflyA_inv(L, tw, b);
        #pragma unroll
        for (int s = 0; s < 8; ++s) Z[(b + 16 * s) * RS + cp] = L[s];
    }
}
// colB: lanes span 64 columns (c = tid&127) so banks vary across a wave.
__device__ inline void f_colB(f2* Z, const f2* tw, int tid) {        // setup
    int c = tid & 127, g = tid >> 7;
    f2* col = Z + g * 16 * RS + cpad(c);
    f2 M[16];
    #pragma unroll
    for (int s = 0; s < 16; ++s) M[s] = col[s * RS];
    bfly16_fwd(M, tw);
    #pragma unroll
    for (int s = 0; s < 16; ++s) col[s * RS] = M[s];
}
__device__ inline void it_colB(f2* Z, const f2* tw, const f2* Vfg, int tid) {
    int c = tid & 127, g = tid >> 7;
    f2* col = Z + g * 16 * RS + cpad(c);
    const f2* vf = Vfg + g * 16 * 128 + c;
    f2 M[16];
    #pragma unroll
    for (int s = 0; s < 16; ++s) M[s] = col[s * RS];
    bfly16_fwd(M, tw);
    #pragma unroll
    for (int s = 0; s < 16; ++s) M[s] = cmulf(M[s], vf[s * 128]);
    bfly16_inv(M, tw);
    #pragma unroll
    for (int s = 0; s < 16; ++s) col[s * RS] = M[s];
}

// One-barrier block reduce: >=1 barrier separates reuses of the same buffer.
__device__ inline double blk_reduce(double v, double* red, int wid, int m) {
    #pragma unroll
    for (int off = 32; off > 0; off >>= 1) v += __shfl_down(v, off);
    if (m == 0) red[wid] = v;
    __syncthreads();
    double s = 0.0;
    #pragma unroll
    for (int i = 0; i < 16; ++i) s += red[i];
    return s;
}

// ---------------------------------------------------------------------------
// k_cg_solve: R11-exact (958 us). Vf setup + 50 CG iterations, one launch.
// ---------------------------------------------------------------------------
__global__ __launch_bounds__(1024, 4) void k_cg_solve(
        const float* __restrict__ vcf, float* __restrict__ Vf,
        const double2* __restrict__ rvec, const float* __restrict__ wsv,
        const float* __restrict__ sig2, double2* __restrict__ xg,
        float* __restrict__ alg)
{
    __shared__ f2 Z[128 * RS];
    __shared__ f2 tw[64];
    __shared__ double redA[16], redB[16], redC[16];

    int tid = threadIdx.x;
    int wid = tid >> 6, m = tid & 63;

    if (tid < 64) {
        float sn, cs;
        sincospif(-(float)tid / 64.f, &sn, &cs);
        tw[tid] = (f2){cs, sn};
    }
    __syncthreads();

    // ---- Vf setup (forward transform of vc, scrambled order)
    for (int i = tid; i < 16384; i += 1024)
        Z[(i >> 7) * RS + cpad(i & 127)] = ((const f2*)vcf)[i];
    __syncthreads();
    f_rowA(Z, tw, tid, 128, false); __syncthreads();
    f_rowB(Z, tw, tid, 128);        __syncthreads();
    f_colA(Z, tw, tid, false);      __syncthreads();
    f_colB(Z, tw, tid);             __syncthreads();
    for (int i = tid; i < 16384; i += 1024)
        ((f2*)Vf)[i] = Z[(i >> 7) * RS + cpad(i & 127)];
    __syncthreads();

    // ---- CG state (p, r in regs; x in global)
    double2 pR[4], rR[4];
    float wsr[4];
    int zix[4];
    double rzp = 0.0;
    #pragma unroll
    for (int s = 0; s < 4; ++s) {
        int e = tid + (s << 10);
        double2 bv = rvec[e];
        pR[s] = bv; rR[s] = bv;
        wsr[s] = wsv[e];
        zix[s] = (e >> 6) * RS + cpad(e & 63);
        xg[e] = make_double2(0.0, 0.0);
        rzp += bv.x * bv.x + bv.y * bv.y;
    }
    double rz = blk_reduce(rzp, redC, wid, m);
    double s2 = (double)sig2[0];
    const double inv16384 = 1.0 / 16384.0;
    __syncthreads();

    for (int it = 0; it < 50; ++it) {
        // scatter z = ws*p into rows<64, cols<64 (rest synthesized as zero)
        #pragma unroll
        for (int s = 0; s < 4; ++s)
            Z[zix[s]] = (f2){(float)((double)wsr[s] * pR[s].x),
                             (float)((double)wsr[s] * pR[s].y)};
        __syncthreads();

        f_rowA(Z, tw, tid, 64, true);           __syncthreads();
        f_rowB(Z, tw, tid, 64);                 __syncthreads();
        f_colA(Z, tw, tid, true);               __syncthreads();
        it_colB(Z, tw, (const f2*)Vf, tid);     __syncthreads();
        i_colA(Z, tw, tid);                     __syncthreads();
        i_rowB(Z, tw, tid, 64);                 __syncthreads();
        i_rowA(Z, tw, tid, 64);                 __syncthreads();

        // Ap, <p,Ap>
        f2 tz[4];
        double papp = 0.0;
        #pragma unroll
        for (int s = 0; s < 4; ++s) {
            tz[s] = Z[zix[s]];
            double apx = (double)wsr[s] * (double)tz[s].x * inv16384 + s2 * pR[s].x;
            double apy = (double)wsr[s] * (double)tz[s].y * inv16384 + s2 * pR[s].y;
            papp += pR[s].x * apx + pR[s].y * apy;
        }
        double pap = blk_reduce(papp, redA, wid, m);
        double alpha = rz / (pap + 1e-30);

        double rrp = 0.0;
        #pragma unroll
        for (int s = 0; s < 4; ++s) {
            int e = tid + (s << 10);
            double apx = (double)wsr[s] * (double)tz[s].x * inv16384 + s2 * pR[s].x;
            double apy = (double)wsr[s] * (double)tz[s].y * inv16384 + s2 * pR[s].y;
            double2 xv = xg[e];
            xv.x += alpha * pR[s].x; xv.y += alpha * pR[s].y;
            xg[e] = xv;
            rR[s].x -= alpha * apx; rR[s].y -= alpha * apy;
            rrp += rR[s].x * rR[s].x + rR[s].y * rR[s].y;
        }
        double rzn = blk_reduce(rrp, redB, wid, m);
        double beta = rzn / (rz + 1e-30);
        rz = rzn;
        #pragma unroll
        for (int s = 0; s < 4; ++s) {
            pR[s].x = rR[s].x + beta * pR[s].x;
            pR[s].y = rR[s].y + beta * pR[s].y;
        }
    }

    // al = ws * x_50
    #pragma unroll
    for (int s = 0; s < 4; ++s) {
        int e = tid + (s << 10);
        double2 xv = xg[e];
        ((f2*)alg)[e] = (f2){(float)((double)wsr[s] * xv.x),
                             (float)((double)wsr[s] * xv.y)};
    }
}

// ---------------------------------------------------------------------------
// k_eval (unchanged)
// ---------------------------------------------------------------------------
__global__ __launch_bounds__(64) void k_eval(const float* __restrict__ xnew,
                                             const float* __restrict__ alg,
                                             float* __restrict__ out, int B)
{
    __shared__ float2 al[4096];
    int t = threadIdx.x;
    int b = blockIdx.x * 64 + t;
    for (int i = t; i < 4096; i += 64) {
        f2 v = ((const f2*)alg)[i];
        al[i] = make_float2(v.x, v.y);
    }
    float x0 = 0.f, x1 = 0.f;
    if (b < B) { x0 = xnew[2 * b]; x1 = xnew[2 * b + 1]; }
    __syncthreads();
    double2 wstep; { double sn, cs; sincospi((double)x1, &sn, &cs); wstep = make_double2(cs, sn); }
    double mu = 0.0;
    for (int jg = 0; jg < 4; ++jg) {
        float2 tacc[16];
        for (int q = 0; q < 16; ++q) tacc[q] = make_float2(0.f, 0.f);
        double2 e2; { double sn, cs; sincospi(-32.0 * (double)x1, &sn, &cs); e2 = make_double2(cs, sn); }
        for (int k = 0; k < 64; ++k) {
            float2 e2f = make_float2((float)e2.x, (float)e2.y);
            for (int q = 0; q < 16; ++q) {
                int j = jg * 16 + q;
                float2 a = al[j * 64 + k];
                tacc[q].x += a.x * e2f.x - a.y * e2f.y;
                tacc[q].y += a.x * e2f.y + a.y * e2f.x;
            }
            e2 = make_double2(e2.x * wstep.x - e2.y * wstep.y,
                              e2.x * wstep.y + e2.y * wstep.x);
        }
        for (int q = 0; q < 16; ++q) {
            int j = jg * 16 + q;
            double sn, cs;
            sincospi((double)x0 * (double)(j - 32), &sn, &cs);
            mu += cs * (double)tacc[q].x - sn * (double)tacc[q].y;
        }
    }
    if (b < B) out[b] = (float)mu;
}

// ---------------------------------------------------------------------------

extern "C" void kernel_launch(void* const* d_in, const int* in_sizes, int n_in,
                              void* d_out, int out_size, void* d_ws, size_t ws_size,
                              hipStream_t stream)
{
    const float* x    = (const float*)d_in[0];
    const float* y    = (const float*)d_in[1];
    const float* xnew = (const float*)d_in[2];
    const float* wsv  = (const float*)d_in[3];
    const float* sig2 = (const float*)d_in[4];
    int N = in_sizes[1];
    int B = in_sizes[2] / 2;

    char* base = (char*)d_ws;
    size_t o = 0;
    float*   vcf  = (float*)(base + o);   o += 131072;   // 128x128 circulant vc (fp32)
    float*   Vf   = (float*)(base + o);   o += 131072;   // scrambled 2D FFT of vc
    double2* rvec = (double2*)(base + o); o += 65536;    // b = ws*Fy (fp64)
    double2* xg   = (double2*)(base + o); o += 65536;    // CG solution x (fp64)
    float*   alg  = (float*)(base + o);   o += 32768;    // ws*x_50 (fp32 complex)
    size_t avail = (ws_size > o) ? ws_size - o : 0;
    int cv = (int)(avail / 139264);                      // 128KB v + 8KB fy per unit
    if (cv > 768) cv = 768;                              // R13: raised 384->768
    if (cv < 16) cv = 16;                                //   (grid was the
    cv &= ~15;                                           //    occupancy binder)
    int cf = cv / 4;
    float* pv = (float*)(base + o); o += (size_t)cv * 131072;
    float* pf = (float*)(base + o);

    hipMemsetAsync(vcf, 0, 131072, stream);              // fp32 atomic target

    k_outer<<<cv + cf, 256, 0, stream>>>(x, y, pv, pf, N, cv, cf);
    k_reduce<<<528, 256, 0, stream>>>(pv, pf, wsv, vcf, rvec, cv, cf);
    k_cg_solve<<<1, 1024, 0, stream>>>(vcf, Vf, rvec, wsv, sig2, xg, alg);
    k_eval<<<(B + 63) / 64, 64, 0, stream>>>(xnew, alg, (float*)d_out, B);
}